// Round 1
// baseline (453.567 us; speedup 1.0000x reference)
//
#include <hip/hip_runtime.h>
#include <stdint.h>

// ---------------- problem constants (fixed by setup_inputs) ----------------
#define G       69
#define BATCH   8
// sparse_shape (Z,Y,X) = (32,512,512), window (12,12,32), SHIFT=true
// mwx = ceil(512/12)+1 = 44, mwy = 44, mwz = ceil(32/32)+1 = 2
#define MPS     3872        // 44*44*2
#define VOL     4608        // 12*12*32
// max key = (7*3872 + 43*88 + 43*2 + 1)*4608 + 11*384 + 11*32 + 31 = 142,737,407
#define WORDS      4460544u // ceil(142737408 / 32)  (exact: 4460544*32 = 142737408)
#define CHUNK_WORDS 4096
#define NCHUNKS    1089     // WORDS / CHUNK_WORDS (exact)
#define WPT        16       // words per thread; 256 threads * 16 = 4096

// ctrl layout (int32 indices)
#define C_COUNTS 0   // [8]
#define C_BS     8   // [9]
#define C_CP     17  // [8]
#define C_BSP    25  // [9]

// ---------------- batch histogram ----------------
__global__ void hist_kernel(const int* __restrict__ coords, int N, int* __restrict__ ctrl) {
    int c0=0,c1=0,c2=0,c3=0,c4=0,c5=0,c6=0,c7=0;
    for (int i = blockIdx.x*blockDim.x + threadIdx.x; i < N; i += gridDim.x*blockDim.x) {
        int b = coords[i*4];
        c0 += (b==0); c1 += (b==1); c2 += (b==2); c3 += (b==3);
        c4 += (b==4); c5 += (b==5); c6 += (b==6); c7 += (b==7);
    }
    __shared__ int h[BATCH];
    if (threadIdx.x < BATCH) h[threadIdx.x] = 0;
    __syncthreads();
    atomicAdd(&h[0],c0); atomicAdd(&h[1],c1); atomicAdd(&h[2],c2); atomicAdd(&h[3],c3);
    atomicAdd(&h[4],c4); atomicAdd(&h[5],c5); atomicAdd(&h[6],c6); atomicAdd(&h[7],c7);
    __syncthreads();
    if (threadIdx.x < BATCH) atomicAdd(&ctrl[C_COUNTS + threadIdx.x], h[threadIdx.x]);
}

// ---------------- tiny prefix prep (1 thread) ----------------
__global__ void prep_kernel(int* __restrict__ ctrl) {
    if (threadIdx.x == 0 && blockIdx.x == 0) {
        int bs = 0, bsp = 0;
        ctrl[C_BS] = 0; ctrl[C_BSP] = 0;
        for (int b = 0; b < BATCH; b++) {
            int n  = ctrl[C_COUNTS + b];
            int np = ((n + G - 1) / G) * G;
            ctrl[C_CP + b] = np;
            bs += n; bsp += np;
            ctrl[C_BS + b + 1]  = bs;
            ctrl[C_BSP + b + 1] = bsp;
        }
    }
}

// ---------------- key computation helper ----------------
__device__ __forceinline__ void keys_from_coord(int4 c, unsigned& kx, unsigned& ky) {
    int b  = c.x;
    int zz = c.y + 16;   // z + win_z/2
    int yy = c.z + 6;    // y + win_y/2
    int xx = c.w + 6;    // x + win_x/2
    int wx = xx / 12, cx = xx - wx*12;
    int wy = yy / 12, cy = yy - wy*12;
    int wz = zz >> 5, cz = zz & 31;
    int bwx = b*MPS + wx*88 + wy*2 + wz;   // mwy*mwz = 88, mwz = 2
    int bwy = b*MPS + wy*88 + wx*2 + wz;   // mwx*mwz = 88
    kx = (unsigned)(bwx*VOL + cx*384 + cy*32 + cz);  // win_y*win_z = 384
    ky = (unsigned)(bwy*VOL + cy*384 + cx*32 + cz);  // win_x*win_z = 384
}

// ---------------- per-point: win2flat + set bits in both bitmaps ----------------
__global__ void points_kernel(const int4* __restrict__ coords, int N,
                              const int* __restrict__ ctrl,
                              int* __restrict__ win2flat,
                              unsigned* __restrict__ bitsX, unsigned* __restrict__ bitsY) {
    __shared__ int s_off[BATCH];
    if (threadIdx.x < BATCH)
        s_off[threadIdx.x] = ctrl[C_BSP + threadIdx.x] - ctrl[C_BS + threadIdx.x];
    __syncthreads();
    int i = blockIdx.x*blockDim.x + threadIdx.x;
    if (i >= N) return;
    int4 c = coords[i];
    win2flat[i] = i + s_off[c.x];
    unsigned kx, ky;
    keys_from_coord(c, kx, ky);
    atomicOr(&bitsX[kx >> 5], 1u << (kx & 31));
    atomicOr(&bitsY[ky >> 5], 1u << (ky & 31));
}

// ---------------- flat2win (closed form over padded index space) ----------------
__global__ void f2w_kernel(int Np, const int* __restrict__ ctrl, int* __restrict__ out) {
    __shared__ int s_bs[BATCH+1], s_bsp[BATCH+1], s_cnt[BATCH], s_cp[BATCH];
    int t = threadIdx.x;
    if (t < BATCH)   { s_cnt[t] = ctrl[C_COUNTS+t]; s_cp[t] = ctrl[C_CP+t]; }
    if (t < BATCH+1) { s_bs[t]  = ctrl[C_BS+t];     s_bsp[t] = ctrl[C_BSP+t]; }
    __syncthreads();
    int j = blockIdx.x*blockDim.x + t;
    if (j >= Np) return;
    int b = 0;
    #pragma unroll
    for (int k = 1; k < BATCH; k++) b += (j >= s_bsp[k]);
    int off  = s_bsp[b] - s_bs[b];
    int num  = s_cnt[b], nump = s_cp[b];
    int r    = num % G;
    int tail_start = (num != nump) ? (s_bsp[b+1] - G + r) : s_bsp[b+1];
    int v;
    if (j < tail_start)       v = j - off;
    else if (nump != G)       v = j - G - off;
    else { int tt = j - tail_start; int m = num > 0 ? num : 1; v = s_bs[b] + tt % m; }
    out[j] = v;
}

// ---------------- scan pass 1: per-chunk popcount sums (both maps via blockIdx.y) ----------------
__global__ void scan1_kernel(const unsigned* __restrict__ bits0, unsigned* __restrict__ chunkSums) {
    const unsigned* bits = bits0 + (size_t)blockIdx.y * WORDS;
    unsigned* cs = chunkSums + blockIdx.y * NCHUNKS;
    unsigned base = blockIdx.x * CHUNK_WORDS + threadIdx.x * WPT;
    unsigned s = 0;
    #pragma unroll
    for (int k = 0; k < WPT/4; k++) {
        uint4 v = ((const uint4*)(bits + base))[k];
        s += __popc(v.x) + __popc(v.y) + __popc(v.z) + __popc(v.w);
    }
    __shared__ unsigned red[256];
    red[threadIdx.x] = s; __syncthreads();
    for (int d = 128; d > 0; d >>= 1) {
        if (threadIdx.x < d) red[threadIdx.x] += red[threadIdx.x + d];
        __syncthreads();
    }
    if (threadIdx.x == 0) cs[blockIdx.x] = red[0];
}

// ---------------- scan pass 2: exclusive scan of chunk sums (single block per map) ----------------
__global__ void scan2_kernel(unsigned* __restrict__ chunkSums) {
    unsigned* cs = chunkSums + blockIdx.y * NCHUNKS;
    __shared__ unsigned sc[256];
    __shared__ unsigned s_run;
    int t = threadIdx.x;
    if (t == 0) s_run = 0;
    __syncthreads();
    for (int base = 0; base < NCHUNKS; base += 256) {
        unsigned v = (base + t < NCHUNKS) ? cs[base + t] : 0;
        sc[t] = v; __syncthreads();
        for (int d = 1; d < 256; d <<= 1) {
            unsigned u = (t >= d) ? sc[t - d] : 0;
            __syncthreads();
            sc[t] += u;
            __syncthreads();
        }
        unsigned incl = sc[t];
        unsigned tot  = sc[255];
        unsigned run  = s_run;
        if (base + t < NCHUNKS) cs[base + t] = run + incl - v;
        __syncthreads();
        if (t == 0) s_run = run + tot;
        __syncthreads();
    }
}

// ---------------- scan pass 3: per-word exclusive popcount prefix ----------------
__global__ void scan3_kernel(const unsigned* __restrict__ bits0,
                             const unsigned* __restrict__ chunkSums,
                             unsigned* __restrict__ prefix0) {
    const unsigned* bits   = bits0   + (size_t)blockIdx.y * WORDS;
    unsigned*       prefix = prefix0 + (size_t)blockIdx.y * WORDS;
    const unsigned* cs = chunkSums + blockIdx.y * NCHUNKS;
    unsigned base = blockIdx.x * CHUNK_WORDS + threadIdx.x * WPT;
    unsigned w[WPT];
    unsigned s = 0;
    #pragma unroll
    for (int k = 0; k < WPT/4; k++) {
        uint4 v = ((const uint4*)(bits + base))[k];
        w[4*k] = v.x; w[4*k+1] = v.y; w[4*k+2] = v.z; w[4*k+3] = v.w;
        s += __popc(v.x) + __popc(v.y) + __popc(v.z) + __popc(v.w);
    }
    __shared__ unsigned sc[256];
    sc[threadIdx.x] = s; __syncthreads();
    for (int d = 1; d < 256; d <<= 1) {
        unsigned u = (threadIdx.x >= d) ? sc[threadIdx.x - d] : 0;
        __syncthreads();
        sc[threadIdx.x] += u;
        __syncthreads();
    }
    unsigned excl = sc[threadIdx.x] - s + cs[blockIdx.x];
    unsigned out[WPT];
    #pragma unroll
    for (int k = 0; k < WPT; k++) { out[k] = excl; excl += __popc(w[k]); }
    #pragma unroll
    for (int k = 0; k < WPT/4; k++) {
        uint4 v; v.x = out[4*k]; v.y = out[4*k+1]; v.z = out[4*k+2]; v.w = out[4*k+3];
        ((uint4*)(prefix + base))[k] = v;
    }
}

// ---------------- scatter: map[rank(key)] = i ----------------
__global__ void scatter_kernel(const int4* __restrict__ coords, int N,
                               const unsigned* __restrict__ bitsX, const unsigned* __restrict__ bitsY,
                               const unsigned* __restrict__ prefX, const unsigned* __restrict__ prefY,
                               int* __restrict__ xmap, int* __restrict__ ymap) {
    int i = blockIdx.x*blockDim.x + threadIdx.x;
    if (i >= N) return;
    int4 c = coords[i];
    unsigned kx, ky;
    keys_from_coord(c, kx, ky);
    unsigned wx = kx >> 5, bx = kx & 31;
    unsigned rx = prefX[wx] + __popc(bitsX[wx] & ((1u << bx) - 1u));
    xmap[rx] = i;
    unsigned wy = ky >> 5, by = ky & 31;
    unsigned ry = prefY[wy] + __popc(bitsY[wy] & ((1u << by) - 1u));
    ymap[ry] = i;
}

// ---------------- launch ----------------
extern "C" void kernel_launch(void* const* d_in, const int* in_sizes, int n_in,
                              void* d_out, int out_size, void* d_ws, size_t ws_size,
                              hipStream_t stream) {
    const int* coords = (const int*)d_in[0];
    int N  = in_sizes[0] / 4;
    int Np = out_size - 3 * N;

    char* ws = (char*)d_ws;
    int*      ctrl      = (int*)(ws + 0);                  // 256 B
    unsigned* chunkSums = (unsigned*)(ws + 256);           // 2*1089*4 B (< 16 KiB reserved)
    unsigned* bitsX     = (unsigned*)(ws + 16640);         // 17,842,176 B
    unsigned* bitsY     = bitsX + WORDS;                   // contiguous
    unsigned* prefX     = bitsY + WORDS;
    unsigned* prefY     = prefX + WORDS;
    // total ws: 16640 + 4*WORDS*4 = 71,385,344 bytes

    int* out  = (int*)d_out;
    int* f2w  = out;
    int* w2f  = out + Np;
    int* xmap = out + Np + N;
    int* ymap = out + Np + 2*N;

    hipMemsetAsync(ctrl, 0, 256, stream);
    hipMemsetAsync(bitsX, 0, (size_t)2 * WORDS * 4, stream);

    hist_kernel<<<1024, 256, 0, stream>>>(coords, N, ctrl);
    prep_kernel<<<1, 64, 0, stream>>>(ctrl);
    points_kernel<<<(N + 255)/256, 256, 0, stream>>>((const int4*)coords, N, ctrl, w2f, bitsX, bitsY);
    f2w_kernel<<<(Np + 255)/256, 256, 0, stream>>>(Np, ctrl, f2w);
    scan1_kernel<<<dim3(NCHUNKS, 2), 256, 0, stream>>>(bitsX, chunkSums);
    scan2_kernel<<<dim3(1, 2), 256, 0, stream>>>(chunkSums);
    scan3_kernel<<<dim3(NCHUNKS, 2), 256, 0, stream>>>(bitsX, chunkSums, prefX);
    scatter_kernel<<<(N + 255)/256, 256, 0, stream>>>((const int4*)coords, N,
                                                      bitsX, bitsY, prefX, prefY, xmap, ymap);
}